// Round 3
// baseline (200.315 us; speedup 1.0000x reference)
//
#include <hip/hip_runtime.h>

#define DI __device__ __forceinline__

typedef __attribute__((ext_vector_type(8))) short short8;
typedef __attribute__((ext_vector_type(4))) float f32x4;

// ---------- helpers ----------
DI ushort f2bf(float f) {
  union { float f; unsigned u; } v; v.f = f;
  unsigned r = v.u + 0x7fffu + ((v.u >> 16) & 1u);
  return (ushort)(r >> 16);
}

DI void gload_lds16(const void* g, void* l) {
  __builtin_amdgcn_global_load_lds((const __attribute__((address_space(1))) void*)g,
                                   (__attribute__((address_space(3))) void*)l, 16, 0, 0);
}

// ---------- 1. M = I + 0.1 * sum_w bi_w[w] * bi_basis[w]  (512x512) ----------
__global__ __launch_bounds__(256) void k_biW(const float2* __restrict__ bb,
                                             const float* __restrict__ bw,
                                             float2* __restrict__ Mf32,
                                             uint* __restrict__ Mbf16) {
  __shared__ float w[128];
  int tid = threadIdx.x;
  if (tid < 128) w[tid] = bw[tid];
  __syncthreads();
  int t = blockIdx.x * 256 + tid;            // 131072 threads, 2 elems each
  const float2* p = bb + t;
  float ax = 0.f, ay = 0.f;
#pragma unroll 8
  for (int k = 0; k < 128; ++k) {
    float2 v = p[(size_t)k * 131072];
    float s = w[k];
    ax += s * v.x; ay += s * v.y;
  }
  int i = t >> 8, j0 = (t & 255) * 2;
  float2 r;
  r.x = 0.1f * ax + (i == j0 + 0 ? 1.f : 0.f);
  r.y = 0.1f * ay + (i == j0 + 1 ? 1.f : 0.f);
  Mf32[t] = r;
  Mbf16[t] = (uint)f2bf(r.x) | ((uint)f2bf(r.y) << 16);
}

// ---------- 2. y = A @ v  (512x512 * 512), one wave per output ----------
__global__ __launch_bounds__(256) void k_matvec(const float* __restrict__ A,
                                                const float* __restrict__ v,
                                                float* __restrict__ y) {
  int o = blockIdx.x * 4 + (threadIdx.x >> 6);
  int lane = threadIdx.x & 63;
  float acc = 0.f;
  for (int k = lane; k < 512; k += 64) acc += A[o * 512 + k] * v[k];
#pragma unroll
  for (int s = 32; s; s >>= 1) acc += __shfl_down(acc, s, 64);
  if (lane == 0) y[o] = acc;
}

// ---------- 3. lazy_P -> Wt bf16, Wt[(nb*512+i)*512 + o] = W[o, nb*512+i] ----------
__global__ __launch_bounds__(256) void k_lazyP(const float* __restrict__ LW,
                                               const float* __restrict__ Pa,
                                               const float* __restrict__ Pb8,
                                               const int* __restrict__ perm,
                                               ushort* __restrict__ Wt) {
  int q = blockIdx.x * 256 + threadIdx.x;    // 262144 threads
  int r = perm[q];
  int o = r >> 9, ic = r & 511;
  if (q < 131072) {                          // term a: s=4
    int ii = q & 3;
    int base = q - ii;
    int r0 = perm[base], r1 = perm[base + 1], r2 = perm[base + 2], r3 = perm[base + 3];
    float p0 = Pa[ii * 4 + 0], p1 = Pa[ii * 4 + 1], p2 = Pa[ii * 4 + 2], p3 = Pa[ii * 4 + 3];
    int a0 = (r0 >> 9) * 4608 + (r0 & 511);
    int a1 = (r1 >> 9) * 4608 + (r1 & 511);
    int a2 = (r2 >> 9) * 4608 + (r2 & 511);
    int a3 = (r3 >> 9) * 4608 + (r3 & 511);
#pragma unroll
    for (int c = 0; c < 9; ++c) {
      int off = c * 512;
      float acc = p0 * LW[a0 + off] + p1 * LW[a1 + off] + p2 * LW[a2 + off] + p3 * LW[a3 + off];
      Wt[(size_t)(c * 512 + ic) * 512 + o] = f2bf(acc);
    }
  } else {                                   // term b: s=8
    int l2 = q - 131072;
    int ii = l2 & 7;
    int base = q - ii;
    int rr[8]; int aa[8]; float pp[8];
#pragma unroll
    for (int j = 0; j < 8; ++j) {
      rr[j] = perm[base + j];
      aa[j] = (rr[j] >> 9) * 4608 + (rr[j] & 511);
      pp[j] = Pb8[ii * 8 + j];
    }
#pragma unroll
    for (int c = 0; c < 9; ++c) {
      int off = c * 512;
      float acc = 0.f;
#pragma unroll
      for (int j = 0; j < 8; ++j) acc += pp[j] * LW[aa[j] + off];
      Wt[(size_t)(c * 512 + ic) * 512 + o] = f2bf(acc);
    }
  }
}

// ---------- 4. acts bf16 (8192 x 4608) ----------
__global__ __launch_bounds__(256) void k_acts(const float* __restrict__ x,
                                              const float* __restrict__ grid,
                                              const int* __restrict__ u,
                                              const int* __restrict__ indices,
                                              ushort* __restrict__ acts) {
  __shared__ float basis[8][64][9];
  __shared__ int sidx[512];
  int tid = threadIdx.x;
  int b0 = blockIdx.x * 8;
  for (int i = tid; i < 512; i += 256) sidx[i] = indices[i];
  // phase 1: 8 rows x 64 gated channels -> 9 basis values each
#pragma unroll
  for (int e0 = 0; e0 < 2; ++e0) {
    int e = e0 * 256 + tid;
    int row = e >> 6, j = e & 63;
    float gs = x[(size_t)(b0 + row) * 576 + u[j]];
    float g0 = grid[j * 6], g5 = grid[j * 6 + 5];
    float h = (g5 - g0) * 0.2f;
    float lo = g0 - 3.f * h;
    float tt = (gs - lo) / h;
#pragma unroll
    for (int n = 0; n < 8; ++n) basis[row][j][n] = 0.f;
    float fc = floorf(tt);
    int c = (int)fc;
    if (c >= 0 && c <= 10) {
      float t = tt - fc;
      float t2 = t * t, t3 = t2 * t;
      float om = 1.f - t;
      float w0 = t3 * (1.f / 6.f);                                    // i = c
      float w1 = (1.f + 3.f * t + 3.f * t2 - 3.f * t3) * (1.f / 6.f); // i = c-1
      float w2 = (4.f - 6.f * t2 + 3.f * t3) * (1.f / 6.f);           // i = c-2
      float w3 = om * om * om * (1.f / 6.f);                          // i = c-3
      if (c <= 7) basis[row][j][c] = w0;
      if (c >= 1 && c <= 8) basis[row][j][c - 1] = w1;
      if (c >= 2 && c <= 9) basis[row][j][c - 2] = w2;
      if (c >= 3) basis[row][j][c - 3] = w3;
    }
    basis[row][j][8] = gs / (1.f + __expf(-gs));   // silu
  }
  __syncthreads();
  // phase 2: each thread owns (row, 8-wide i-chunk); 16B stores for all 9 bases.
#pragma unroll
  for (int rep = 0; rep < 2; ++rep) {
    int e = rep * 256 + tid;                 // 0..511 = 8 rows x 64 chunks
    int row = e >> 6, i0 = (e & 63) * 8;
    size_t xb = (size_t)(b0 + row) * 576;
    float4 xa = *(const float4*)&x[xb + i0];
    float4 xc = *(const float4*)&x[xb + i0 + 4];
    int4 ja = *(const int4*)&sidx[i0];
    int4 jb = *(const int4*)&sidx[i0 + 4];
    size_t ab = (size_t)(b0 + row) * 4608 + i0;
#pragma unroll
    for (int n = 0; n < 9; ++n) {
      short8 hv;
      hv[0] = (short)f2bf(basis[row][ja.x][n] * xa.x);
      hv[1] = (short)f2bf(basis[row][ja.y][n] * xa.y);
      hv[2] = (short)f2bf(basis[row][ja.z][n] * xa.z);
      hv[3] = (short)f2bf(basis[row][ja.w][n] * xa.w);
      hv[4] = (short)f2bf(basis[row][jb.x][n] * xc.x);
      hv[5] = (short)f2bf(basis[row][jb.y][n] * xc.y);
      hv[6] = (short)f2bf(basis[row][jb.z][n] * xc.z);
      hv[7] = (short)f2bf(basis[row][jb.w][n] * xc.w);
      *(short8*)(&acts[ab + (size_t)n * 512]) = hv;
    }
  }
}

// ---------- 5. GEMM: C[m,n] = sum_k A[m,k]*B[n,k] (+bias[n]) ----------
// A: (M x Kd) bf16 row-major, B: (N x Kd) bf16 row-major ("B^T" form)
// Double-buffered prefetch 2-phase (T3-minimum): STAGE(next) issued BEFORE
// compute(cur); single barrier per K-step; the barrier's implicit vmcnt(0)
// drain for next-tile loads is covered by this tile's ds_read+MFMA.
// XCD-aware swizzle (requires gridDim.x % 8 == 0 — true at both call sites).
template <int BM, int BN, bool BIAS, bool OUTBF>
__global__ __launch_bounds__(256, 2) void gemm_bt(const ushort* __restrict__ A,
                                                  const ushort* __restrict__ B,
                                                  void* __restrict__ Cout,
                                                  const float* __restrict__ bias,
                                                  int N, int Kd) {
  constexpr int BK = 64;
  constexpr int FM = BM / 32;   // frags per wave in M (wave covers BM/2 rows)
  constexpr int FN = BN / 32;   // frags per wave in N (wave covers BN/2 cols)
  __shared__ __align__(16) ushort Al[2][BM * BK];
  __shared__ __align__(16) ushort Bl[2][BN * BK];
  int tid = threadIdx.x, lane = tid & 63, wid = tid >> 6;
  int wm = wid >> 1, wn = wid & 1;
  int tiles_n = N / BN;
  int per_xcd = gridDim.x >> 3;
  int flat = (blockIdx.x & 7) * per_xcd + (blockIdx.x >> 3);
  int bm = flat / tiles_n, bn = flat % tiles_n;
  long m0 = (long)bm * BM;
  long n0 = (long)bn * BN;

  // per-thread staging coords (constant over K-steps)
  const ushort* agp = A + (m0 + (tid >> 3)) * (long)Kd + (tid & 7) * 8;
  const ushort* bgp = B + (n0 + (tid >> 3)) * (long)Kd + (tid & 7) * 8;

#define STAGE(buf, k0)                                                       \
  do {                                                                       \
    _Pragma("unroll")                                                        \
    for (int it = 0; it < BM / 32; ++it)                                     \
      gload_lds16(agp + (it * 32) * (long)Kd + (k0), &Al[buf][(it * 256 + tid) * 8]); \
    _Pragma("unroll")                                                        \
    for (int it = 0; it < BN / 32; ++it)                                     \
      gload_lds16(bgp + (it * 32) * (long)Kd + (k0), &Bl[buf][(it * 256 + tid) * 8]); \
  } while (0)

  f32x4 acc[FM][FN] = {};
  int nt = Kd / BK;
  STAGE(0, 0);
  __syncthreads();                      // vmcnt(0) drain of prologue stage
  for (int t = 0; t < nt; ++t) {
    int cur = t & 1;
    if (t + 1 < nt) STAGE(cur ^ 1, (t + 1) * BK);   // prefetch flies under compute
#pragma unroll
    for (int ks = 0; ks < 2; ++ks) {
      short8 a[FM], b[FN];
#pragma unroll
      for (int f = 0; f < FM; ++f)
        a[f] = *(const short8*)&Al[cur][(wm * (FM * 16) + f * 16 + (lane & 15)) * BK + ks * 32 + (lane >> 4) * 8];
#pragma unroll
      for (int f = 0; f < FN; ++f)
        b[f] = *(const short8*)&Bl[cur][(wn * (FN * 16) + f * 16 + (lane & 15)) * BK + ks * 32 + (lane >> 4) * 8];
#pragma unroll
      for (int i = 0; i < FM; ++i)
#pragma unroll
        for (int j = 0; j < FN; ++j)
          acc[i][j] = __builtin_amdgcn_mfma_f32_16x16x32_bf16(a[i], b[j], acc[i][j], 0, 0, 0);
    }
    __syncthreads();                    // next buffer staged; cur reads done
  }
#undef STAGE
#pragma unroll
  for (int i = 0; i < FM; ++i)
#pragma unroll
    for (int j = 0; j < FN; ++j) {
      int row_b = wm * (FM * 16) + i * 16 + ((lane >> 4) * 4);
      long col = n0 + wn * (FN * 16) + j * 16 + (lane & 15);
      float bv = BIAS ? bias[col] : 0.f;
#pragma unroll
      for (int r = 0; r < 4; ++r) {
        long row = m0 + row_b + r;
        float v = acc[i][j][r] + bv;
        if (OUTBF) ((ushort*)Cout)[row * N + col] = f2bf(v);
        else       ((float*)Cout)[row * N + col] = v;
      }
    }
}

// ---------- launch ----------
extern "C" void kernel_launch(void* const* d_in, const int* in_sizes, int n_in,
                              void* d_out, int out_size, void* d_ws, size_t ws_size,
                              hipStream_t stream) {
  const float* x        = (const float*)d_in[0];
  const float* grid     = (const float*)d_in[1];
  const float* LW       = (const float*)d_in[2];
  const float* lb       = (const float*)d_in[3];
  const float* Pa       = (const float*)d_in[4];
  const float* Pb8      = (const float*)d_in[5];
  const float* Pbm      = (const float*)d_in[6];
  const float* bi_basis = (const float*)d_in[7];
  const float* bi_w     = (const float*)d_in[8];
  const int*   u        = (const int*)d_in[9];
  const int*   indices  = (const int*)d_in[10];
  const int*   perm     = (const int*)d_in[11];
  float* out = (float*)d_out;
  char* ws = (char*)d_ws;

  float*  Mf32  = (float*)(ws + 0);               // 1 MB
  ushort* Mbf16 = (ushort*)(ws + 1048576);        // 0.5 MB
  float*  tvec  = (float*)(ws + 1572864);         // 2 KB
  float*  b2    = (float*)(ws + 1576960);         // 2 KB
  ushort* Wt    = (ushort*)(ws + 2097152);        // 4.5 MB   (4608 x 512 bf16)
  ushort* W2    = (ushort*)(ws + 6815744);        // 4.5 MB   (512 x 4608 bf16)
  ushort* acts  = (ushort*)(ws + 11534336);       // 72 MB    (8192 x 4608 bf16)

  // 1. M = I + 0.1 * bi_w . bi_basis
  k_biW<<<512, 256, 0, stream>>>((const float2*)bi_basis, bi_w, (float2*)Mf32, (uint*)Mbf16);
  // 2. t = Pb @ lb ; b2 = M @ t
  k_matvec<<<128, 256, 0, stream>>>(Pbm, lb, tvec);
  k_matvec<<<128, 256, 0, stream>>>(Mf32, tvec, b2);
  // 3. lazy_P -> Wt (bf16, (K=4608) x (N=512))
  k_lazyP<<<1024, 256, 0, stream>>>(LW, Pa, Pb8, perm, Wt);
  // 4. W2[o,c] = sum_k M[o,k] * Wt[c,k]   (M=512, N=4608, K=512)
  gemm_bt<128, 64, false, true><<<(512 / 128) * (4608 / 64), 256, 0, stream>>>(
      Mbf16, Wt, (void*)W2, nullptr, 4608, 512);
  // 5. acts
  k_acts<<<1024, 256, 0, stream>>>(x, grid, u, indices, acts);
  // 6. out = acts @ W2^T + b2   (M=8192, N=512, K=4608)
  gemm_bt<128, 64, true, false><<<(8192 / 128) * (512 / 64), 256, 0, stream>>>(
      acts, W2, (void*)out, b2, 512, 4608);
}

// Round 4
// 187.738 us; speedup vs baseline: 1.0670x; 1.0670x over previous
//
#include <hip/hip_runtime.h>

#define DI __device__ __forceinline__

typedef __attribute__((ext_vector_type(8))) short short8;
typedef __attribute__((ext_vector_type(4))) float f32x4;

// ---------- helpers ----------
DI ushort f2bf(float f) {
  union { float f; unsigned u; } v; v.f = f;
  unsigned r = v.u + 0x7fffu + ((v.u >> 16) & 1u);
  return (ushort)(r >> 16);
}

DI void gload_lds16(const void* g, void* l) {
  __builtin_amdgcn_global_load_lds((const __attribute__((address_space(1))) void*)g,
                                   (__attribute__((address_space(3))) void*)l, 16, 0, 0);
}

// ---------- 1. M = I + 0.1 * sum_w bi_w[w] * bi_basis[w]  (512x512) ----------
__global__ __launch_bounds__(256) void k_biW(const float2* __restrict__ bb,
                                             const float* __restrict__ bw,
                                             float2* __restrict__ Mf32,
                                             uint* __restrict__ Mbf16) {
  __shared__ float w[128];
  int tid = threadIdx.x;
  if (tid < 128) w[tid] = bw[tid];
  __syncthreads();
  int t = blockIdx.x * 256 + tid;            // 131072 threads, 2 elems each
  const float2* p = bb + t;
  float ax = 0.f, ay = 0.f;
#pragma unroll 8
  for (int k = 0; k < 128; ++k) {
    float2 v = p[(size_t)k * 131072];
    float s = w[k];
    ax += s * v.x; ay += s * v.y;
  }
  int i = t >> 8, j0 = (t & 255) * 2;
  float2 r;
  r.x = 0.1f * ax + (i == j0 + 0 ? 1.f : 0.f);
  r.y = 0.1f * ay + (i == j0 + 1 ? 1.f : 0.f);
  Mf32[t] = r;
  Mbf16[t] = (uint)f2bf(r.x) | ((uint)f2bf(r.y) << 16);
}

// ---------- 2. y = A @ v  (512x512 * 512), one wave per output ----------
__global__ __launch_bounds__(256) void k_matvec(const float* __restrict__ A,
                                                const float* __restrict__ v,
                                                float* __restrict__ y) {
  int o = blockIdx.x * 4 + (threadIdx.x >> 6);
  int lane = threadIdx.x & 63;
  float acc = 0.f;
  for (int k = lane; k < 512; k += 64) acc += A[o * 512 + k] * v[k];
#pragma unroll
  for (int s = 32; s; s >>= 1) acc += __shfl_down(acc, s, 64);
  if (lane == 0) y[o] = acc;
}

// ---------- 3. lazy_P -> Wt bf16, Wt[(nb*512+i)*512 + o] = W[o, nb*512+i] ----------
__global__ __launch_bounds__(256) void k_lazyP(const float* __restrict__ LW,
                                               const float* __restrict__ Pa,
                                               const float* __restrict__ Pb8,
                                               const int* __restrict__ perm,
                                               ushort* __restrict__ Wt) {
  int q = blockIdx.x * 256 + threadIdx.x;    // 262144 threads
  int r = perm[q];
  int o = r >> 9, ic = r & 511;
  if (q < 131072) {                          // term a: s=4
    int ii = q & 3;
    int base = q - ii;
    int r0 = perm[base], r1 = perm[base + 1], r2 = perm[base + 2], r3 = perm[base + 3];
    float p0 = Pa[ii * 4 + 0], p1 = Pa[ii * 4 + 1], p2 = Pa[ii * 4 + 2], p3 = Pa[ii * 4 + 3];
    int a0 = (r0 >> 9) * 4608 + (r0 & 511);
    int a1 = (r1 >> 9) * 4608 + (r1 & 511);
    int a2 = (r2 >> 9) * 4608 + (r2 & 511);
    int a3 = (r3 >> 9) * 4608 + (r3 & 511);
#pragma unroll
    for (int c = 0; c < 9; ++c) {
      int off = c * 512;
      float acc = p0 * LW[a0 + off] + p1 * LW[a1 + off] + p2 * LW[a2 + off] + p3 * LW[a3 + off];
      Wt[(size_t)(c * 512 + ic) * 512 + o] = f2bf(acc);
    }
  } else {                                   // term b: s=8
    int l2 = q - 131072;
    int ii = l2 & 7;
    int base = q - ii;
    int rr[8]; int aa[8]; float pp[8];
#pragma unroll
    for (int j = 0; j < 8; ++j) {
      rr[j] = perm[base + j];
      aa[j] = (rr[j] >> 9) * 4608 + (rr[j] & 511);
      pp[j] = Pb8[ii * 8 + j];
    }
#pragma unroll
    for (int c = 0; c < 9; ++c) {
      int off = c * 512;
      float acc = 0.f;
#pragma unroll
      for (int j = 0; j < 8; ++j) acc += pp[j] * LW[aa[j] + off];
      Wt[(size_t)(c * 512 + ic) * 512 + o] = f2bf(acc);
    }
  }
}

// ---------- 4. acts bf16 (8192 x 4608) ----------
__global__ __launch_bounds__(256) void k_acts(const float* __restrict__ x,
                                              const float* __restrict__ grid,
                                              const int* __restrict__ u,
                                              const int* __restrict__ indices,
                                              ushort* __restrict__ acts) {
  __shared__ float basis[8][64][9];
  __shared__ int sidx[512];
  int tid = threadIdx.x;
  int b0 = blockIdx.x * 8;
  for (int i = tid; i < 512; i += 256) sidx[i] = indices[i];
  // phase 1: 8 rows x 64 gated channels -> 9 basis values each
#pragma unroll
  for (int e0 = 0; e0 < 2; ++e0) {
    int e = e0 * 256 + tid;
    int row = e >> 6, j = e & 63;
    float gs = x[(size_t)(b0 + row) * 576 + u[j]];
    float g0 = grid[j * 6], g5 = grid[j * 6 + 5];
    float h = (g5 - g0) * 0.2f;
    float lo = g0 - 3.f * h;
    float tt = (gs - lo) / h;
#pragma unroll
    for (int n = 0; n < 8; ++n) basis[row][j][n] = 0.f;
    float fc = floorf(tt);
    int c = (int)fc;
    if (c >= 0 && c <= 10) {
      float t = tt - fc;
      float t2 = t * t, t3 = t2 * t;
      float om = 1.f - t;
      float w0 = t3 * (1.f / 6.f);                                    // i = c
      float w1 = (1.f + 3.f * t + 3.f * t2 - 3.f * t3) * (1.f / 6.f); // i = c-1
      float w2 = (4.f - 6.f * t2 + 3.f * t3) * (1.f / 6.f);           // i = c-2
      float w3 = om * om * om * (1.f / 6.f);                          // i = c-3
      if (c <= 7) basis[row][j][c] = w0;
      if (c >= 1 && c <= 8) basis[row][j][c - 1] = w1;
      if (c >= 2 && c <= 9) basis[row][j][c - 2] = w2;
      if (c >= 3) basis[row][j][c - 3] = w3;
    }
    basis[row][j][8] = gs / (1.f + __expf(-gs));   // silu
  }
  __syncthreads();
  // phase 2: each thread owns (row, 8-wide i-chunk); 16B stores for all 9 bases.
#pragma unroll
  for (int rep = 0; rep < 2; ++rep) {
    int e = rep * 256 + tid;                 // 0..511 = 8 rows x 64 chunks
    int row = e >> 6, i0 = (e & 63) * 8;
    size_t xb = (size_t)(b0 + row) * 576;
    float4 xa = *(const float4*)&x[xb + i0];
    float4 xc = *(const float4*)&x[xb + i0 + 4];
    int4 ja = *(const int4*)&sidx[i0];
    int4 jb = *(const int4*)&sidx[i0 + 4];
    size_t ab = (size_t)(b0 + row) * 4608 + i0;
#pragma unroll
    for (int n = 0; n < 9; ++n) {
      short8 hv;
      hv[0] = (short)f2bf(basis[row][ja.x][n] * xa.x);
      hv[1] = (short)f2bf(basis[row][ja.y][n] * xa.y);
      hv[2] = (short)f2bf(basis[row][ja.z][n] * xa.z);
      hv[3] = (short)f2bf(basis[row][ja.w][n] * xa.w);
      hv[4] = (short)f2bf(basis[row][jb.x][n] * xc.x);
      hv[5] = (short)f2bf(basis[row][jb.y][n] * xc.y);
      hv[6] = (short)f2bf(basis[row][jb.z][n] * xc.z);
      hv[7] = (short)f2bf(basis[row][jb.w][n] * xc.w);
      *(short8*)(&acts[ab + (size_t)n * 512]) = hv;
    }
  }
}

// ---------- 5. GEMM: C[m,n] = sum_k A[m,k]*B[n,k] (+bias[n]) ----------
// A: (M x Kd) bf16 row-major, B: (N x Kd) bf16 row-major ("B^T" form).
// 128x128 tile, 4 waves (2x2), FM=FN=4 -> 0.5 ds_read per MFMA.
// T2 XOR swizzle (both-sides, rule #21): global SOURCE chunk pre-swizzled
// (c ^= row&7) while global_load_lds dest stays linear; ds_read index XORs
// the same pattern -> 16-way bank conflict becomes 2-way (free).
// Double-buffered prefetch-before-compute (needed: grid gives 1 block/CU).
// XCD-aware swizzle (gridDim.x % 8 == 0 at both call sites).
template <int BM, int BN, bool BIAS, bool OUTBF>
__global__ __launch_bounds__(256) void gemm_bt(const ushort* __restrict__ A,
                                               const ushort* __restrict__ B,
                                               void* __restrict__ Cout,
                                               const float* __restrict__ bias,
                                               int N, int Kd) {
  constexpr int BK = 64;
  constexpr int FM = BM / 32;   // frags per wave in M (2x2 wave grid)
  constexpr int FN = BN / 32;
  __shared__ __align__(16) ushort Al[2][BM * BK];
  __shared__ __align__(16) ushort Bl[2][BN * BK];
  int tid = threadIdx.x, lane = tid & 63, wid = tid >> 6;
  int wm = wid >> 1, wn = wid & 1;
  int tiles_n = N / BN;
  int per_xcd = gridDim.x >> 3;
  int flat = (blockIdx.x & 7) * per_xcd + (blockIdx.x >> 3);
  int bm = flat / tiles_n, bn = flat % tiles_n;
  long m0 = (long)bm * BM;
  long n0 = (long)bn * BN;

  // staging: thread -> row r = tid>>3, 16B chunk c = tid&7, source chunk
  // pre-swizzled by row (r&7). Rows advance by 32 per it -> r&7 invariant.
  int swc = ((tid & 7) ^ ((tid >> 3) & 7)) * 8;     // swizzled k-offset (ushorts)
  const ushort* agp = A + (m0 + (tid >> 3)) * (long)Kd + swc;
  const ushort* bgp = B + (n0 + (tid >> 3)) * (long)Kd + swc;

#define STAGE(buf, k0)                                                        \
  do {                                                                        \
    _Pragma("unroll")                                                         \
    for (int it = 0; it < BM / 32; ++it)                                      \
      gload_lds16(agp + (it * 32) * (long)Kd + (k0), &Al[buf][(it * 256 + tid) * 8]); \
    _Pragma("unroll")                                                         \
    for (int it = 0; it < BN / 32; ++it)                                      \
      gload_lds16(bgp + (it * 32) * (long)Kd + (k0), &Bl[buf][(it * 256 + tid) * 8]); \
  } while (0)

  f32x4 acc[FM][FN] = {};
  int swz = (lane & 7) << 3;                  // read-side XOR (ushort units)
  int nt = Kd / BK;
  STAGE(0, 0);
  __syncthreads();
  for (int t = 0; t < nt; ++t) {
    int cur = t & 1;
    if (t + 1 < nt) STAGE(cur ^ 1, (t + 1) * BK);   // flies under compute
#pragma unroll
    for (int ks = 0; ks < 2; ++ks) {
      int kidx = (ks * 32 + (lane >> 4) * 8) ^ swz;
      short8 a[FM], b[FN];
#pragma unroll
      for (int f = 0; f < FM; ++f)
        a[f] = *(const short8*)&Al[cur][(wm * (FM * 16) + f * 16 + (lane & 15)) * BK + kidx];
#pragma unroll
      for (int f = 0; f < FN; ++f)
        b[f] = *(const short8*)&Bl[cur][(wn * (FN * 16) + f * 16 + (lane & 15)) * BK + kidx];
#pragma unroll
      for (int i = 0; i < FM; ++i)
#pragma unroll
        for (int j = 0; j < FN; ++j)
          acc[i][j] = __builtin_amdgcn_mfma_f32_16x16x32_bf16(a[i], b[j], acc[i][j], 0, 0, 0);
    }
    __syncthreads();
  }
#undef STAGE
#pragma unroll
  for (int i = 0; i < FM; ++i)
#pragma unroll
    for (int j = 0; j < FN; ++j) {
      int row_b = wm * (FM * 16) + i * 16 + ((lane >> 4) * 4);
      long col = n0 + wn * (FN * 16) + j * 16 + (lane & 15);
      float bv = BIAS ? bias[col] : 0.f;
#pragma unroll
      for (int r = 0; r < 4; ++r) {
        long row = m0 + row_b + r;
        float v = acc[i][j][r] + bv;
        if (OUTBF) ((ushort*)Cout)[row * N + col] = f2bf(v);
        else       ((float*)Cout)[row * N + col] = v;
      }
    }
}

// ---------- launch ----------
extern "C" void kernel_launch(void* const* d_in, const int* in_sizes, int n_in,
                              void* d_out, int out_size, void* d_ws, size_t ws_size,
                              hipStream_t stream) {
  const float* x        = (const float*)d_in[0];
  const float* grid     = (const float*)d_in[1];
  const float* LW       = (const float*)d_in[2];
  const float* lb       = (const float*)d_in[3];
  const float* Pa       = (const float*)d_in[4];
  const float* Pb8      = (const float*)d_in[5];
  const float* Pbm      = (const float*)d_in[6];
  const float* bi_basis = (const float*)d_in[7];
  const float* bi_w     = (const float*)d_in[8];
  const int*   u        = (const int*)d_in[9];
  const int*   indices  = (const int*)d_in[10];
  const int*   perm     = (const int*)d_in[11];
  float* out = (float*)d_out;
  char* ws = (char*)d_ws;

  float*  Mf32  = (float*)(ws + 0);               // 1 MB
  ushort* Mbf16 = (ushort*)(ws + 1048576);        // 0.5 MB
  float*  tvec  = (float*)(ws + 1572864);         // 2 KB
  float*  b2    = (float*)(ws + 1576960);         // 2 KB
  ushort* Wt    = (ushort*)(ws + 2097152);        // 4.5 MB   (4608 x 512 bf16)
  ushort* W2    = (ushort*)(ws + 6815744);        // 4.5 MB   (512 x 4608 bf16)
  ushort* acts  = (ushort*)(ws + 11534336);       // 72 MB    (8192 x 4608 bf16)

  // 1. M = I + 0.1 * bi_w . bi_basis
  k_biW<<<512, 256, 0, stream>>>((const float2*)bi_basis, bi_w, (float2*)Mf32, (uint*)Mbf16);
  // 2. t = Pb @ lb ; b2 = M @ t
  k_matvec<<<128, 256, 0, stream>>>(Pbm, lb, tvec);
  k_matvec<<<128, 256, 0, stream>>>(Mf32, tvec, b2);
  // 3. lazy_P -> Wt (bf16, (K=4608) x (N=512))
  k_lazyP<<<1024, 256, 0, stream>>>(LW, Pa, Pb8, perm, Wt);
  // 4. W2[o,c] = sum_k M[o,k] * Wt[c,k]   (M=512, N=4608, K=512), grid 144
  gemm_bt<128, 128, false, true><<<(512 / 128) * (4608 / 128), 256, 0, stream>>>(
      Mbf16, Wt, (void*)W2, nullptr, 4608, 512);
  // 5. acts
  k_acts<<<1024, 256, 0, stream>>>(x, grid, u, indices, acts);
  // 6. out = acts @ W2^T + b2   (M=8192, N=512, K=4608), grid 256
  gemm_bt<128, 128, true, false><<<(8192 / 128) * (512 / 128), 256, 0, stream>>>(
      acts, W2, (void*)out, b2, 512, 4608);
}

// Round 5
// 167.215 us; speedup vs baseline: 1.1979x; 1.1227x over previous
//
#include <hip/hip_runtime.h>

#define DI __device__ __forceinline__

typedef __attribute__((ext_vector_type(8))) short short8;
typedef __attribute__((ext_vector_type(4))) float f32x4;

// ---------- helpers ----------
DI ushort f2bf(float f) {
  union { float f; unsigned u; } v; v.f = f;
  unsigned r = v.u + 0x7fffu + ((v.u >> 16) & 1u);
  return (ushort)(r >> 16);
}

DI void gload_lds16(const void* g, void* l) {
  __builtin_amdgcn_global_load_lds((const __attribute__((address_space(1))) void*)g,
                                   (__attribute__((address_space(3))) void*)l, 16, 0, 0);
}

// ---------- 1. M = I + 0.1 * sum_w bi_w[w] * bi_basis[w]  (512x512) ----------
__global__ __launch_bounds__(256) void k_biW(const float2* __restrict__ bb,
                                             const float* __restrict__ bw,
                                             float2* __restrict__ Mf32,
                                             uint* __restrict__ Mbf16) {
  __shared__ float w[128];
  int tid = threadIdx.x;
  if (tid < 128) w[tid] = bw[tid];
  __syncthreads();
  int t = blockIdx.x * 256 + tid;            // 131072 threads, 2 elems each
  const float2* p = bb + t;
  float ax = 0.f, ay = 0.f;
#pragma unroll 8
  for (int k = 0; k < 128; ++k) {
    float2 v = p[(size_t)k * 131072];
    float s = w[k];
    ax += s * v.x; ay += s * v.y;
  }
  int i = t >> 8, j0 = (t & 255) * 2;
  float2 r;
  r.x = 0.1f * ax + (i == j0 + 0 ? 1.f : 0.f);
  r.y = 0.1f * ay + (i == j0 + 1 ? 1.f : 0.f);
  Mf32[t] = r;
  Mbf16[t] = (uint)f2bf(r.x) | ((uint)f2bf(r.y) << 16);
}

// ---------- 2. y = A @ v  (512x512 * 512), one wave per output ----------
__global__ __launch_bounds__(256) void k_matvec(const float* __restrict__ A,
                                                const float* __restrict__ v,
                                                float* __restrict__ y) {
  int o = blockIdx.x * 4 + (threadIdx.x >> 6);
  int lane = threadIdx.x & 63;
  float acc = 0.f;
  for (int k = lane; k < 512; k += 64) acc += A[o * 512 + k] * v[k];
#pragma unroll
  for (int s = 32; s; s >>= 1) acc += __shfl_down(acc, s, 64);
  if (lane == 0) y[o] = acc;
}

// ---------- 3. lazy_P -> Wt bf16 ----------
// Each lane loads ONLY its own permuted row's 9 values; the P-mix within each
// 4-lane (term a) / 8-lane (term b) group is done with __shfl broadcasts
// (removes the 4x/8x redundant scattered L2 reads of the previous version).
__global__ __launch_bounds__(256) void k_lazyP(const float* __restrict__ LW,
                                               const float* __restrict__ Pa,
                                               const float* __restrict__ Pb8,
                                               const int* __restrict__ perm,
                                               ushort* __restrict__ Wt) {
  int q = blockIdx.x * 256 + threadIdx.x;    // 262144 threads
  int lane = threadIdx.x & 63;
  int r = perm[q];
  int o = r >> 9, ic = r & 511;
  int a_own = o * 4608 + ic;                 // own row base in LW (W layout o*4608 + c*512 + ic handled via +c*512)
  if (q < 131072) {                          // term a: s=4, groups of 4 lanes
    int ii = lane & 3, g = lane & ~3;
    float pp[4];
#pragma unroll
    for (int j = 0; j < 4; ++j) pp[j] = Pa[ii * 4 + j];
#pragma unroll
    for (int c = 0; c < 9; ++c) {
      float v = LW[a_own + c * 512];
      float acc = 0.f;
#pragma unroll
      for (int j = 0; j < 4; ++j) acc += pp[j] * __shfl(v, g + j, 64);
      Wt[(size_t)(c * 512 + ic) * 512 + o] = f2bf(acc);
    }
  } else {                                   // term b: s=8, groups of 8 lanes
    int ii = lane & 7, g = lane & ~7;
    float pp[8];
#pragma unroll
    for (int j = 0; j < 8; ++j) pp[j] = Pb8[ii * 8 + j];
#pragma unroll
    for (int c = 0; c < 9; ++c) {
      float v = LW[a_own + c * 512];
      float acc = 0.f;
#pragma unroll
      for (int j = 0; j < 8; ++j) acc += pp[j] * __shfl(v, g + j, 64);
      Wt[(size_t)(c * 512 + ic) * 512 + o] = f2bf(acc);
    }
  }
}

// ---------- 4. acts bf16 (8192 x 4608) ----------
__global__ __launch_bounds__(256) void k_acts(const float* __restrict__ x,
                                              const float* __restrict__ grid,
                                              const int* __restrict__ u,
                                              const int* __restrict__ indices,
                                              ushort* __restrict__ acts) {
  __shared__ float basis[8][64][9];
  __shared__ int sidx[512];
  int tid = threadIdx.x;
  int b0 = blockIdx.x * 8;
  for (int i = tid; i < 512; i += 256) sidx[i] = indices[i];
  // phase 1: 8 rows x 64 gated channels -> 9 basis values each
#pragma unroll
  for (int e0 = 0; e0 < 2; ++e0) {
    int e = e0 * 256 + tid;
    int row = e >> 6, j = e & 63;
    float gs = x[(size_t)(b0 + row) * 576 + u[j]];
    float g0 = grid[j * 6], g5 = grid[j * 6 + 5];
    float h = (g5 - g0) * 0.2f;
    float lo = g0 - 3.f * h;
    float tt = (gs - lo) / h;
#pragma unroll
    for (int n = 0; n < 8; ++n) basis[row][j][n] = 0.f;
    float fc = floorf(tt);
    int c = (int)fc;
    if (c >= 0 && c <= 10) {
      float t = tt - fc;
      float t2 = t * t, t3 = t2 * t;
      float om = 1.f - t;
      float w0 = t3 * (1.f / 6.f);
      float w1 = (1.f + 3.f * t + 3.f * t2 - 3.f * t3) * (1.f / 6.f);
      float w2 = (4.f - 6.f * t2 + 3.f * t3) * (1.f / 6.f);
      float w3 = om * om * om * (1.f / 6.f);
      if (c <= 7) basis[row][j][c] = w0;
      if (c >= 1 && c <= 8) basis[row][j][c - 1] = w1;
      if (c >= 2 && c <= 9) basis[row][j][c - 2] = w2;
      if (c >= 3) basis[row][j][c - 3] = w3;
    }
    basis[row][j][8] = gs / (1.f + __expf(-gs));   // silu
  }
  __syncthreads();
  // phase 2: each thread owns (row, 8-wide i-chunk); 16B stores for all 9 bases.
#pragma unroll
  for (int rep = 0; rep < 2; ++rep) {
    int e = rep * 256 + tid;
    int row = e >> 6, i0 = (e & 63) * 8;
    size_t xb = (size_t)(b0 + row) * 576;
    float4 xa = *(const float4*)&x[xb + i0];
    float4 xc = *(const float4*)&x[xb + i0 + 4];
    int4 ja = *(const int4*)&sidx[i0];
    int4 jb = *(const int4*)&sidx[i0 + 4];
    size_t ab = (size_t)(b0 + row) * 4608 + i0;
#pragma unroll
    for (int n = 0; n < 9; ++n) {
      short8 hv;
      hv[0] = (short)f2bf(basis[row][ja.x][n] * xa.x);
      hv[1] = (short)f2bf(basis[row][ja.y][n] * xa.y);
      hv[2] = (short)f2bf(basis[row][ja.z][n] * xa.z);
      hv[3] = (short)f2bf(basis[row][ja.w][n] * xa.w);
      hv[4] = (short)f2bf(basis[row][jb.x][n] * xc.x);
      hv[5] = (short)f2bf(basis[row][jb.y][n] * xc.y);
      hv[6] = (short)f2bf(basis[row][jb.z][n] * xc.z);
      hv[7] = (short)f2bf(basis[row][jb.w][n] * xc.w);
      *(short8*)(&acts[ab + (size_t)n * 512]) = hv;
    }
  }
}

// ---------- 5a. W2 GEMM (non-split): C[m,n] = sum_k A[m,k]*B[n,k], bf16 out ----
template <int BM, int BN>
__global__ __launch_bounds__(256) void gemm_bt(const ushort* __restrict__ A,
                                               const ushort* __restrict__ B,
                                               ushort* __restrict__ Cout,
                                               int N, int Kd) {
  constexpr int BK = 64;
  constexpr int FM = BM / 32;
  constexpr int FN = BN / 32;
  __shared__ __align__(16) ushort Al[2][BM * BK];
  __shared__ __align__(16) ushort Bl[2][BN * BK];
  int tid = threadIdx.x, lane = tid & 63, wid = tid >> 6;
  int wm = wid >> 1, wn = wid & 1;
  int tiles_n = N / BN;
  int per_xcd = gridDim.x >> 3;
  int flat = (blockIdx.x & 7) * per_xcd + (blockIdx.x >> 3);
  int bm = flat / tiles_n, bn = flat % tiles_n;
  long m0 = (long)bm * BM;
  long n0 = (long)bn * BN;
  int swc = ((tid & 7) ^ ((tid >> 3) & 7)) * 8;
  const ushort* agp = A + (m0 + (tid >> 3)) * (long)Kd + swc;
  const ushort* bgp = B + (n0 + (tid >> 3)) * (long)Kd + swc;

#define STAGE(buf, k0)                                                        \
  do {                                                                        \
    _Pragma("unroll")                                                         \
    for (int it = 0; it < BM / 32; ++it)                                      \
      gload_lds16(agp + (it * 32) * (long)Kd + (k0), &Al[buf][(it * 256 + tid) * 8]); \
    _Pragma("unroll")                                                         \
    for (int it = 0; it < BN / 32; ++it)                                      \
      gload_lds16(bgp + (it * 32) * (long)Kd + (k0), &Bl[buf][(it * 256 + tid) * 8]); \
  } while (0)

  f32x4 acc[FM][FN] = {};
  int swz = (lane & 7) << 3;
  int nt = Kd / BK;
  STAGE(0, 0);
  __syncthreads();
  for (int t = 0; t < nt; ++t) {
    int cur = t & 1;
    if (t + 1 < nt) STAGE(cur ^ 1, (t + 1) * BK);
#pragma unroll
    for (int ks = 0; ks < 2; ++ks) {
      int kidx = (ks * 32 + (lane >> 4) * 8) ^ swz;
      short8 a[FM], b[FN];
#pragma unroll
      for (int f = 0; f < FM; ++f)
        a[f] = *(const short8*)&Al[cur][(wm * (FM * 16) + f * 16 + (lane & 15)) * BK + kidx];
#pragma unroll
      for (int f = 0; f < FN; ++f)
        b[f] = *(const short8*)&Bl[cur][(wn * (FN * 16) + f * 16 + (lane & 15)) * BK + kidx];
#pragma unroll
      for (int i = 0; i < FM; ++i)
#pragma unroll
        for (int j = 0; j < FN; ++j)
          acc[i][j] = __builtin_amdgcn_mfma_f32_16x16x32_bf16(a[i], b[j], acc[i][j], 0, 0, 0);
    }
    __syncthreads();
  }
#undef STAGE
#pragma unroll
  for (int i = 0; i < FM; ++i)
#pragma unroll
    for (int j = 0; j < FN; ++j) {
      int row_b = wm * (FM * 16) + i * 16 + ((lane >> 4) * 4);
      long col = n0 + wn * (FN * 16) + j * 16 + (lane & 15);
#pragma unroll
      for (int r = 0; r < 4; ++r)
        Cout[(m0 + row_b + r) * N + col] = f2bf(acc[i][j][r]);
    }
}

// ---------- 5b. main GEMM, split-K x2 ----------
// grid 512: flat -> (kb, bm, bn). 2 blocks/CU (64KB LDS each) restores TLP
// (8 waves/CU) that R4 lost; conflict-free swizzle kept. kb=0 -> P0 (=d_out
// storage, f32), kb=1 -> P1 (ws). k_reduce sums + bias afterwards.
__global__ __launch_bounds__(256, 2) void gemm_sk(const ushort* __restrict__ A,
                                                  const ushort* __restrict__ B,
                                                  float* __restrict__ P0,
                                                  float* __restrict__ P1) {
  constexpr int BM = 128, BN = 128, BK = 64, FM = 4, FN = 4;
  const int Kd = 4608, N = 512;
  __shared__ __align__(16) ushort Al[2][BM * BK];
  __shared__ __align__(16) ushort Bl[2][BN * BK];
  int tid = threadIdx.x, lane = tid & 63, wid = tid >> 6;
  int wm = wid >> 1, wn = wid & 1;
  int per_xcd = gridDim.x >> 3;                       // 64
  int flat = (blockIdx.x & 7) * per_xcd + (blockIdx.x >> 3);
  int kb = flat >> 8;                                 // 0 or 1
  int rem = flat & 255;
  int bm = rem >> 2, bn = rem & 3;                    // tiles_n = 4
  long m0 = (long)bm * BM;
  long n0 = (long)bn * BN;
  int kbase = kb * (Kd / 2);                          // 0 or 2304
  float* Pout = kb ? P1 : P0;

  int swc = ((tid & 7) ^ ((tid >> 3) & 7)) * 8;
  const ushort* agp = A + (m0 + (tid >> 3)) * (long)Kd + kbase + swc;
  const ushort* bgp = B + (n0 + (tid >> 3)) * (long)Kd + kbase + swc;

#define STAGE(buf, k0)                                                        \
  do {                                                                        \
    _Pragma("unroll")                                                         \
    for (int it = 0; it < 4; ++it)                                            \
      gload_lds16(agp + (it * 32) * (long)Kd + (k0), &Al[buf][(it * 256 + tid) * 8]); \
    _Pragma("unroll")                                                         \
    for (int it = 0; it < 4; ++it)                                            \
      gload_lds16(bgp + (it * 32) * (long)Kd + (k0), &Bl[buf][(it * 256 + tid) * 8]); \
  } while (0)

  f32x4 acc[FM][FN] = {};
  int swz = (lane & 7) << 3;
  const int nt = (Kd / 2) / BK;                       // 36
  STAGE(0, 0);
  __syncthreads();
  for (int t = 0; t < nt; ++t) {
    int cur = t & 1;
    if (t + 1 < nt) STAGE(cur ^ 1, (t + 1) * BK);
#pragma unroll
    for (int ks = 0; ks < 2; ++ks) {
      int kidx = (ks * 32 + (lane >> 4) * 8) ^ swz;
      short8 a[FM], b[FN];
#pragma unroll
      for (int f = 0; f < FM; ++f)
        a[f] = *(const short8*)&Al[cur][(wm * 64 + f * 16 + (lane & 15)) * BK + kidx];
#pragma unroll
      for (int f = 0; f < FN; ++f)
        b[f] = *(const short8*)&Bl[cur][(wn * 64 + f * 16 + (lane & 15)) * BK + kidx];
#pragma unroll
      for (int i = 0; i < FM; ++i)
#pragma unroll
        for (int j = 0; j < FN; ++j)
          acc[i][j] = __builtin_amdgcn_mfma_f32_16x16x32_bf16(a[i], b[j], acc[i][j], 0, 0, 0);
    }
    __syncthreads();
  }
#undef STAGE
#pragma unroll
  for (int i = 0; i < FM; ++i)
#pragma unroll
    for (int j = 0; j < FN; ++j) {
      int row_b = wm * 64 + i * 16 + ((lane >> 4) * 4);
      long col = n0 + wn * 64 + j * 16 + (lane & 15);
#pragma unroll
      for (int r = 0; r < 4; ++r)
        Pout[(m0 + row_b + r) * N + col] = acc[i][j][r];
    }
}

// ---------- 6. out = P0 + P1 + b2 (f32, in-place on P0 = d_out) ----------
__global__ __launch_bounds__(256) void k_reduce(float4* __restrict__ P0,
                                                const float4* __restrict__ P1,
                                                const float4* __restrict__ b2) {
  int t = blockIdx.x * 256 + threadIdx.x;   // 524288 threads x 2 float4
#pragma unroll
  for (int rep = 0; rep < 2; ++rep) {
    int e = rep * 524288 + t;
    float4 a = P0[e], b = P1[e], c = b2[e & 127];
    a.x += b.x + c.x; a.y += b.y + c.y; a.z += b.z + c.z; a.w += b.w + c.w;
    P0[e] = a;
  }
}

// ---------- launch ----------
extern "C" void kernel_launch(void* const* d_in, const int* in_sizes, int n_in,
                              void* d_out, int out_size, void* d_ws, size_t ws_size,
                              hipStream_t stream) {
  const float* x        = (const float*)d_in[0];
  const float* grid     = (const float*)d_in[1];
  const float* LW       = (const float*)d_in[2];
  const float* lb       = (const float*)d_in[3];
  const float* Pa       = (const float*)d_in[4];
  const float* Pb8      = (const float*)d_in[5];
  const float* Pbm      = (const float*)d_in[6];
  const float* bi_basis = (const float*)d_in[7];
  const float* bi_w     = (const float*)d_in[8];
  const int*   u        = (const int*)d_in[9];
  const int*   indices  = (const int*)d_in[10];
  const int*   perm     = (const int*)d_in[11];
  float* out = (float*)d_out;
  char* ws = (char*)d_ws;

  float*  Mf32  = (float*)(ws + 0);               // 1 MB
  ushort* Mbf16 = (ushort*)(ws + 1048576);        // 0.5 MB
  float*  tvec  = (float*)(ws + 1572864);         // 2 KB
  float*  b2    = (float*)(ws + 1576960);         // 2 KB
  ushort* Wt    = (ushort*)(ws + 2097152);        // 4.5 MB   (4608 x 512 bf16)
  ushort* W2    = (ushort*)(ws + 6815744);        // 4.5 MB   (512 x 4608 bf16)
  ushort* acts  = (ushort*)(ws + 11534336);       // 72 MB    (8192 x 4608 bf16)
  float*  P1    = (float*)(ws + 87031808);        // 16 MB    (split-K partial)

  // 1. M = I + 0.1 * bi_w . bi_basis
  k_biW<<<512, 256, 0, stream>>>((const float2*)bi_basis, bi_w, (float2*)Mf32, (uint*)Mbf16);
  // 2. t = Pb @ lb ; b2 = M @ t
  k_matvec<<<128, 256, 0, stream>>>(Pbm, lb, tvec);
  k_matvec<<<128, 256, 0, stream>>>(Mf32, tvec, b2);
  // 3. lazy_P -> Wt (bf16, (K=4608) x (N=512))
  k_lazyP<<<1024, 256, 0, stream>>>(LW, Pa, Pb8, perm, Wt);
  // 4. W2[o,c] = sum_k M[o,k] * Wt[c,k]   (M=512, N=4608, K=512), grid 144
  gemm_bt<128, 128><<<(512 / 128) * (4608 / 128), 256, 0, stream>>>(
      Mbf16, Wt, W2, 4608, 512);
  // 5. acts
  k_acts<<<1024, 256, 0, stream>>>(x, grid, u, indices, acts);
  // 6. main GEMM split-K x2: P0(d_out) and P1 partials
  gemm_sk<<<512, 256, 0, stream>>>(acts, W2, out, P1);
  // 7. out = P0 + P1 + b2
  k_reduce<<<2048, 256, 0, stream>>>((float4*)out, (const float4*)P1, (const float4*)b2);
}